// Round 2
// baseline (1065.411 us; speedup 1.0000x reference)
//
#include <hip/hip_runtime.h>
#include <cstdint>
#include <cstddef>

// Problem constants (B=8, L=1024, E=512, H=8, hd=64)
#define BB 8
#define LL 1024
#define EE 512
#define HH 8
#define HD 64
#define BL (BB * LL)

// ---------------------------------------------------------------------------
// K1: vpe_sum[l][d] = sum_j values_pos_enc[0, l, j, d]   (reads 268 MB)
// grid = L blocks, 256 threads. Lanes cover d (16 quads), 16 j-groups.
// Each wave instruction reads 4 contiguous 256B rows -> 1KB coalesced.
// ---------------------------------------------------------------------------
__global__ __launch_bounds__(256) void k_vpe_sum(const float* __restrict__ vpe,
                                                 float* __restrict__ vs)
{
    const int l  = blockIdx.x;
    const int t  = threadIdx.x;
    const int d4 = (t & 15) * 4;
    const int jg = t >> 4;                       // 0..15
    const float* base = vpe + (size_t)l * LL * HD;
    float a0 = 0.f, a1 = 0.f, a2 = 0.f, a3 = 0.f;
    for (int j = jg; j < LL; j += 16) {
        const float4 v = *(const float4*)(base + (size_t)j * HD + d4);
        a0 += v.x; a1 += v.y; a2 += v.z; a3 += v.w;
    }
    __shared__ float red[16][64];
    red[jg][d4 + 0] = a0; red[jg][d4 + 1] = a1;
    red[jg][d4 + 2] = a2; red[jg][d4 + 3] = a3;
    __syncthreads();
    if (t < 64) {
        float s = 0.f;
#pragma unroll
        for (int g = 0; g < 16; ++g) s += red[g][t];
        vs[l * HD + t] = s;
    }
}

// ---------------------------------------------------------------------------
// K2: per block/head, both streams fused:
//   v_s[row][e] = sum_d x_s[row][h*64+d] * Wv[blk,s,h][e][d]
//   h[row][h*64+e] = sum_s ( LN_hd(v_s + vpe_sum[l]) * g_s + b_s + v_s )
// grid = (BL/64, H); 256 threads. Thread tile: 4 rows x 4 e per stream.
// Key algebra: causal softmax rows sum to exactly 1 (>=1 finite entry,
// active_entries==1) -> attention output == v + vpe_sum; q/k/energy/mask
// path (incl. 268 MB keys_pos_enc) is dead code.
// ---------------------------------------------------------------------------
__global__ __launch_bounds__(256) void k_mha_pair(
    const float* __restrict__ x, const float* __restrict__ z,
    const float* __restrict__ Wv, const float* __restrict__ lng,
    const float* __restrict__ lnb, const float* __restrict__ vs,
    float* __restrict__ hbuf, int blk)
{
    const int h  = blockIdx.y;
    const int r0 = blockIdx.x * 64;
    const int t  = threadIdx.x;
    const int tr = t >> 4;                       // 0..15
    const int tc = t & 15;                       // 0..15

    __shared__ float xs[64][68];
    __shared__ float zs[64][68];
    __shared__ float w0s[64][68];
    __shared__ float w1s[64][68];

    const float* xb = x + (size_t)r0 * EE + h * HD;
    const float* zb = z + (size_t)r0 * EE + h * HD;
    const float* w0 = Wv + ((size_t)(blk * 2 + 0) * HH + h) * (HD * HD);
    const float* w1 = Wv + ((size_t)(blk * 2 + 1) * HH + h) * (HD * HD);

#pragma unroll
    for (int i = 0; i < 4; ++i) {
        const int f = t + 256 * i;
        const int r = f >> 4;
        const int q = (f & 15) * 4;
        *(float4*)&xs[r][q]  = *(const float4*)(xb + (size_t)r * EE + q);
        *(float4*)&zs[r][q]  = *(const float4*)(zb + (size_t)r * EE + q);
        *(float4*)&w0s[r][q] = *(const float4*)(w0 + r * HD + q);
        *(float4*)&w1s[r][q] = *(const float4*)(w1 + r * HD + q);
    }
    __syncthreads();

    float v0[4][4] = {}, v1[4][4] = {};
#pragma unroll 4
    for (int d4 = 0; d4 < HD; d4 += 4) {
        float4 a[4], b[4], wa[4], wb[4];
#pragma unroll
        for (int rr = 0; rr < 4; ++rr) {
            a[rr] = *(const float4*)&xs[tr * 4 + rr][d4];
            b[rr] = *(const float4*)&zs[tr * 4 + rr][d4];
        }
#pragma unroll
        for (int je = 0; je < 4; ++je) {
            wa[je] = *(const float4*)&w0s[tc + 16 * je][d4];
            wb[je] = *(const float4*)&w1s[tc + 16 * je][d4];
        }
#pragma unroll
        for (int rr = 0; rr < 4; ++rr)
#pragma unroll
            for (int je = 0; je < 4; ++je) {
                v0[rr][je] = fmaf(a[rr].x, wa[je].x, v0[rr][je]);
                v0[rr][je] = fmaf(a[rr].y, wa[je].y, v0[rr][je]);
                v0[rr][je] = fmaf(a[rr].z, wa[je].z, v0[rr][je]);
                v0[rr][je] = fmaf(a[rr].w, wa[je].w, v0[rr][je]);
                v1[rr][je] = fmaf(b[rr].x, wb[je].x, v1[rr][je]);
                v1[rr][je] = fmaf(b[rr].y, wb[je].y, v1[rr][je]);
                v1[rr][je] = fmaf(b[rr].z, wb[je].z, v1[rr][je]);
                v1[rr][je] = fmaf(b[rr].w, wb[je].w, v1[rr][je]);
            }
    }

    const float* g0 = lng + ((size_t)(blk * 2 + 0) * HH + h) * HD;
    const float* b0 = lnb + ((size_t)(blk * 2 + 0) * HH + h) * HD;
    const float* g1 = lng + ((size_t)(blk * 2 + 1) * HH + h) * HD;
    const float* b1 = lnb + ((size_t)(blk * 2 + 1) * HH + h) * HD;

    float hacc[4][4];
#pragma unroll
    for (int rr = 0; rr < 4; ++rr) {
        const int rg = r0 + tr * 4 + rr;
        const int l  = rg & (LL - 1);
        const float* vrow = vs + (size_t)l * HD;

        // stream 0
        float vv[4], s1 = 0.f, s2 = 0.f;
#pragma unroll
        for (int je = 0; je < 4; ++je) {
            vv[je] = v0[rr][je] + vrow[tc + 16 * je];
            s1 += vv[je]; s2 += vv[je] * vv[je];
        }
#pragma unroll
        for (int m = 1; m <= 8; m <<= 1) { s1 += __shfl_xor(s1, m); s2 += __shfl_xor(s2, m); }
        float mean = s1 * (1.f / HD);
        float rstd = rsqrtf(s2 * (1.f / HD) - mean * mean + 1e-5f);
#pragma unroll
        for (int je = 0; je < 4; ++je) {
            const int e = tc + 16 * je;
            hacc[rr][je] = (vv[je] - mean) * rstd * g0[e] + b0[e] + v0[rr][je];
        }

        // stream 1
        s1 = 0.f; s2 = 0.f;
#pragma unroll
        for (int je = 0; je < 4; ++je) {
            vv[je] = v1[rr][je] + vrow[tc + 16 * je];
            s1 += vv[je]; s2 += vv[je] * vv[je];
        }
#pragma unroll
        for (int m = 1; m <= 8; m <<= 1) { s1 += __shfl_xor(s1, m); s2 += __shfl_xor(s2, m); }
        mean = s1 * (1.f / HD);
        rstd = rsqrtf(s2 * (1.f / HD) - mean * mean + 1e-5f);
#pragma unroll
        for (int je = 0; je < 4; ++je) {
            const int e = tc + 16 * je;
            hacc[rr][je] += (vv[je] - mean) * rstd * g1[e] + b1[e] + v1[rr][je];
        }
    }

    __syncthreads();                             // xs reads done, reuse as staging
#pragma unroll
    for (int rr = 0; rr < 4; ++rr)
#pragma unroll
        for (int je = 0; je < 4; ++je)
            xs[tr * 4 + rr][tc + 16 * je] = hacc[rr][je];
    __syncthreads();
#pragma unroll
    for (int i = 0; i < 4; ++i) {
        const int f = t + 256 * i;
        const int r = f >> 4;
        const int q = (f & 15) * 4;
        *(float4*)(hbuf + (size_t)(r0 + r) * EE + h * HD + q) = *(const float4*)&xs[r][q];
    }
}

// ---------------------------------------------------------------------------
// K3: C[n,o] = act( sum_k A[n,k]*W[o,k] + bias[o] )
// grid = (BL/64, 4 col-chunks); 256 threads; thread tile 4 rows x 8 cols.
// Per k4-step: 192B LDS for 256 FLOP (0.75 B/FLOP -> LDS cap ~92 TF vs 55 TF
// for the old 2x8 tile). LDS 27.6 KB/block. Wt stride 36 floats -> worst
// 2-way ds_read_b128 conflict (free).
// ---------------------------------------------------------------------------
template <bool RELU>
__global__ __launch_bounds__(256) void k_gemm(const float* __restrict__ A,
                                              const float* __restrict__ W,
                                              const float* __restrict__ bias,
                                              float* __restrict__ Cout)
{
    const int r0 = blockIdx.x * 64;
    const int oc = blockIdx.y;                   // 0..3 (128-col chunk)
    const int t  = threadIdx.x;
    const int tr = t >> 4;                       // 0..15
    const int tc = t & 15;                       // 0..15

    __shared__ float As[64][36];
    __shared__ float Wt[128][36];

    float acc[4][8] = {};

    for (int kk = 0; kk < EE; kk += 32) {
#pragma unroll
        for (int i = 0; i < 2; ++i) {            // stage A tile: 64 rows x 8 quads
            const int f = t + 256 * i;
            const int r = f >> 3, q = (f & 7) * 4;
            *(float4*)&As[r][q] = *(const float4*)&A[(size_t)(r0 + r) * EE + kk + q];
        }
#pragma unroll
        for (int i = 0; i < 4; ++i) {            // stage W tile: 128 rows x 8 quads
            const int f = t + 256 * i;
            const int o = f >> 3, q = (f & 7) * 4;
            *(float4*)&Wt[o][q] = *(const float4*)&W[(size_t)(oc * 128 + o) * EE + kk + q];
        }
        __syncthreads();

#pragma unroll
        for (int k4 = 0; k4 < 32; k4 += 4) {
            float4 a[4], w[8];
#pragma unroll
            for (int rr = 0; rr < 4; ++rr)
                a[rr] = *(const float4*)&As[tr * 4 + rr][k4];
#pragma unroll
            for (int j = 0; j < 8; ++j)
                w[j] = *(const float4*)&Wt[tc + 16 * j][k4];
#pragma unroll
            for (int rr = 0; rr < 4; ++rr)
#pragma unroll
                for (int j = 0; j < 8; ++j) {
                    acc[rr][j] = fmaf(a[rr].x, w[j].x, acc[rr][j]);
                    acc[rr][j] = fmaf(a[rr].y, w[j].y, acc[rr][j]);
                    acc[rr][j] = fmaf(a[rr].z, w[j].z, acc[rr][j]);
                    acc[rr][j] = fmaf(a[rr].w, w[j].w, acc[rr][j]);
                }
        }
        __syncthreads();
    }

#pragma unroll
    for (int j = 0; j < 8; ++j) {
        const int o  = oc * 128 + tc + 16 * j;
        const float bv = bias[o];
#pragma unroll
        for (int rr = 0; rr < 4; ++rr) {
            float v = acc[rr][j] + bv;
            if (RELU) v = fmaxf(v, 0.f);
            Cout[(size_t)(r0 + tr * 4 + rr) * EE + o] = v;
        }
    }
}

// ---------------------------------------------------------------------------
// K4: row LayerNorm over E=512: out = (x - m)*rsqrt(var+eps)*fg + fb
// grid = BL/4; 256 threads = 4 waves, one wave per row, 8 floats/lane.
// ---------------------------------------------------------------------------
__global__ __launch_bounds__(256) void k_ln(const float* __restrict__ X,
                                            const float* __restrict__ g,
                                            const float* __restrict__ b,
                                            float* __restrict__ out)
{
    const int row  = blockIdx.x * 4 + (threadIdx.x >> 6);
    const int lane = threadIdx.x & 63;
    const float* xr = X + (size_t)row * EE;
    const int c0 = lane * 8;
    const float4 u = *(const float4*)(xr + c0);
    const float4 w = *(const float4*)(xr + c0 + 4);
    float s = u.x + u.y + u.z + u.w + w.x + w.y + w.z + w.w;
    float q = u.x*u.x + u.y*u.y + u.z*u.z + u.w*u.w
            + w.x*w.x + w.y*w.y + w.z*w.z + w.w*w.w;
#pragma unroll
    for (int m = 1; m < 64; m <<= 1) { s += __shfl_xor(s, m); q += __shfl_xor(q, m); }
    const float mean = s * (1.f / EE);
    const float rstd = rsqrtf(q * (1.f / EE) - mean * mean + 1e-5f);
    const float4 g0 = *(const float4*)(g + c0);
    const float4 g1 = *(const float4*)(g + c0 + 4);
    const float4 b0 = *(const float4*)(b + c0);
    const float4 b1 = *(const float4*)(b + c0 + 4);
    float4 o0, o1;
    o0.x = (u.x - mean) * rstd * g0.x + b0.x;
    o0.y = (u.y - mean) * rstd * g0.y + b0.y;
    o0.z = (u.z - mean) * rstd * g0.z + b0.z;
    o0.w = (u.w - mean) * rstd * g0.w + b0.w;
    o1.x = (w.x - mean) * rstd * g1.x + b1.x;
    o1.y = (w.y - mean) * rstd * g1.y + b1.y;
    o1.z = (w.z - mean) * rstd * g1.z + b1.z;
    o1.w = (w.w - mean) * rstd * g1.w + b1.w;
    float* orow = out + (size_t)row * EE;
    *(float4*)(orow + c0)     = o0;
    *(float4*)(orow + c0 + 4) = o1;
}

// ---------------------------------------------------------------------------
// Host launch. Inputs (setup_inputs order):
// 0 treatments 1 outcomes 2 covariates 3 active(unused) 4 kpe(unused!) 5 vpe
// 6 Wv 7 Wk(unused) 8 Wq(unused) 9 ln_g 10 ln_b 11 ffW1 12 ffb1 13 ffW2
// 14 ffb2 15 fln_g 16 fln_b
// ws usage: vpe_sum 256 KB + two BLxE fp32 buffers = 33.8 MB total.
// ---------------------------------------------------------------------------
extern "C" void kernel_launch(void* const* d_in, const int* in_sizes, int n_in,
                              void* d_out, int out_size, void* d_ws, size_t ws_size,
                              hipStream_t stream)
{
    const float* treat = (const float*)d_in[0];
    const float* outc  = (const float*)d_in[1];
    const float* cov   = (const float*)d_in[2];
    const float* vpe   = (const float*)d_in[5];
    const float* Wv    = (const float*)d_in[6];
    const float* lng   = (const float*)d_in[9];
    const float* lnb   = (const float*)d_in[10];
    const float* W1    = (const float*)d_in[11];
    const float* b1    = (const float*)d_in[12];
    const float* W2    = (const float*)d_in[13];
    const float* b2    = (const float*)d_in[14];
    const float* fg    = (const float*)d_in[15];
    const float* fb    = (const float*)d_in[16];
    float* out = (float*)d_out;

    float* vs  = (float*)d_ws;                       // [L][64]
    float* hb  = vs + (size_t)LL * HD;               // [BL][E]
    float* ff1 = hb + (size_t)BL * EE;               // [BL][E]

    k_vpe_sum<<<LL, 256, 0, stream>>>(vpe, vs);

    const float* xs_[3] = {treat, outc, cov};
    const float* zs_[3] = {cov, treat, outc};
    for (int i = 0; i < 3; ++i) {
        k_mha_pair<<<dim3(BL / 64, HH), 256, 0, stream>>>(xs_[i], zs_[i], Wv, lng, lnb, vs, hb, i);
        k_gemm<true ><<<dim3(BL / 64, 4), 256, 0, stream>>>(hb,  W1 + (size_t)i * EE * EE, b1 + i * EE, ff1);
        k_gemm<false><<<dim3(BL / 64, 4), 256, 0, stream>>>(ff1, W2 + (size_t)i * EE * EE, b2 + i * EE, hb);
        k_ln<<<BL / 4, 256, 0, stream>>>(hb, fg + i * EE, fb + i * EE, out + (size_t)i * BL * EE);
    }
}

// Round 3
// 760.585 us; speedup vs baseline: 1.4008x; 1.4008x over previous
//
#include <hip/hip_runtime.h>
#include <cstdint>
#include <cstddef>

// Problem constants (B=8, L=1024, E=512, H=8, hd=64)
#define BB 8
#define LL 1024
#define EE 512
#define HH 8
#define HD 64
#define BL (BB * LL)

typedef __attribute__((ext_vector_type(8))) short bf16x8;
typedef __attribute__((ext_vector_type(4))) float f32x4;

struct alignas(8) us4 { unsigned short x, y, z, w; };

__device__ __forceinline__ unsigned short f2bf(float x) {
    union { float f; unsigned u; } v; v.f = x;
    unsigned r = v.u + 0x7fffu + ((v.u >> 16) & 1u);
    return (unsigned short)(r >> 16);
}
__device__ __forceinline__ float bf2f(unsigned short h) {
    union { unsigned u; float f; } v; v.u = (unsigned)h << 16;
    return v.f;
}

// async global->LDS, 16B per lane; LDS dest = wave-uniform base + lane*16
__device__ __forceinline__ void gload16(const void* g, void* l) {
    __builtin_amdgcn_global_load_lds(
        (const __attribute__((address_space(1))) unsigned int*)g,
        (__attribute__((address_space(3))) unsigned int*)l, 16, 0, 0);
}

// ---------------------------------------------------------------------------
// K0: pack W1,W2 (fp32 [3][512][512], rows=o, cols=k) into bf16 hi/lo planes
// in a staging-linear blocked layout:
//   Wb[layer][plane(hi=0,lo=1)][nb(4)][ks(16)][kg(4)][n(128)][8]
// so the GEMM's global_load_lds source is slot*16B linear per (nb,ks).
// ---------------------------------------------------------------------------
__global__ __launch_bounds__(256) void k_prep_w(const float* __restrict__ W1,
                                                const float* __restrict__ W2,
                                                unsigned short* __restrict__ Wb1,
                                                unsigned short* __restrict__ Wb2)
{
    const int gid = blockIdx.x * 256 + threadIdx.x;      // 3*262144 total
    const int layer = gid >> 18;
    const int idx   = gid & 262143;
    const int o = idx >> 9, k = idx & 511;
    const int off = (((o >> 7) * 16 + (k >> 5)) * 4 + ((k >> 3) & 3)) * 1024
                  + (o & 127) * 8 + (k & 7);
    const size_t dl = (size_t)layer * 524288;
    const size_t si = (size_t)layer * 262144 + idx;
    {
        const float x = W1[si];
        const unsigned short h = f2bf(x);
        Wb1[dl + off] = h;
        Wb1[dl + 262144 + off] = f2bf(x - bf2f(h));
    }
    {
        const float x = W2[si];
        const unsigned short h = f2bf(x);
        Wb2[dl + off] = h;
        Wb2[dl + 262144 + off] = f2bf(x - bf2f(h));
    }
}

// ---------------------------------------------------------------------------
// K1: vpe_sum[l][d] = sum_j values_pos_enc[0, l, j, d]   (reads 268 MB)
// ---------------------------------------------------------------------------
__global__ __launch_bounds__(256) void k_vpe_sum(const float* __restrict__ vpe,
                                                 float* __restrict__ vs)
{
    const int l  = blockIdx.x;
    const int t  = threadIdx.x;
    const int d4 = (t & 15) * 4;
    const int jg = t >> 4;
    const float* base = vpe + (size_t)l * LL * HD;
    float a0 = 0.f, a1 = 0.f, a2 = 0.f, a3 = 0.f;
    for (int j = jg; j < LL; j += 16) {
        const float4 v = *(const float4*)(base + (size_t)j * HD + d4);
        a0 += v.x; a1 += v.y; a2 += v.z; a3 += v.w;
    }
    __shared__ float red[16][64];
    red[jg][d4 + 0] = a0; red[jg][d4 + 1] = a1;
    red[jg][d4 + 2] = a2; red[jg][d4 + 3] = a3;
    __syncthreads();
    if (t < 64) {
        float s = 0.f;
#pragma unroll
        for (int g = 0; g < 16; ++g) s += red[g][t];
        vs[l * HD + t] = s;
    }
}

// ---------------------------------------------------------------------------
// K2: per block/head, both streams fused; epilogue emits h as bf16 hi/lo
// planes (the next GEMM's A operand).
// Algebra: causal softmax rows sum to exactly 1 -> attn output == v + vpe_sum.
// ---------------------------------------------------------------------------
__global__ __launch_bounds__(256) void k_mha_pair(
    const float* __restrict__ x, const float* __restrict__ z,
    const float* __restrict__ Wv, const float* __restrict__ lng,
    const float* __restrict__ lnb, const float* __restrict__ vs,
    unsigned short* __restrict__ hhi, unsigned short* __restrict__ hlo, int blk)
{
    const int h  = blockIdx.y;
    const int r0 = blockIdx.x * 64;
    const int t  = threadIdx.x;
    const int tr = t >> 4;
    const int tc = t & 15;

    __shared__ float xs[64][68];
    __shared__ float zs[64][68];
    __shared__ float w0s[64][68];
    __shared__ float w1s[64][68];

    const float* xb = x + (size_t)r0 * EE + h * HD;
    const float* zb = z + (size_t)r0 * EE + h * HD;
    const float* w0 = Wv + ((size_t)(blk * 2 + 0) * HH + h) * (HD * HD);
    const float* w1 = Wv + ((size_t)(blk * 2 + 1) * HH + h) * (HD * HD);

#pragma unroll
    for (int i = 0; i < 4; ++i) {
        const int f = t + 256 * i;
        const int r = f >> 4;
        const int q = (f & 15) * 4;
        *(float4*)&xs[r][q]  = *(const float4*)(xb + (size_t)r * EE + q);
        *(float4*)&zs[r][q]  = *(const float4*)(zb + (size_t)r * EE + q);
        *(float4*)&w0s[r][q] = *(const float4*)(w0 + r * HD + q);
        *(float4*)&w1s[r][q] = *(const float4*)(w1 + r * HD + q);
    }
    __syncthreads();

    float v0[4][4] = {}, v1[4][4] = {};
#pragma unroll 4
    for (int d4 = 0; d4 < HD; d4 += 4) {
        float4 a[4], b[4], wa[4], wb[4];
#pragma unroll
        for (int rr = 0; rr < 4; ++rr) {
            a[rr] = *(const float4*)&xs[tr * 4 + rr][d4];
            b[rr] = *(const float4*)&zs[tr * 4 + rr][d4];
        }
#pragma unroll
        for (int je = 0; je < 4; ++je) {
            wa[je] = *(const float4*)&w0s[tc + 16 * je][d4];
            wb[je] = *(const float4*)&w1s[tc + 16 * je][d4];
        }
#pragma unroll
        for (int rr = 0; rr < 4; ++rr)
#pragma unroll
            for (int je = 0; je < 4; ++je) {
                v0[rr][je] = fmaf(a[rr].x, wa[je].x, v0[rr][je]);
                v0[rr][je] = fmaf(a[rr].y, wa[je].y, v0[rr][je]);
                v0[rr][je] = fmaf(a[rr].z, wa[je].z, v0[rr][je]);
                v0[rr][je] = fmaf(a[rr].w, wa[je].w, v0[rr][je]);
                v1[rr][je] = fmaf(b[rr].x, wb[je].x, v1[rr][je]);
                v1[rr][je] = fmaf(b[rr].y, wb[je].y, v1[rr][je]);
                v1[rr][je] = fmaf(b[rr].z, wb[je].z, v1[rr][je]);
                v1[rr][je] = fmaf(b[rr].w, wb[je].w, v1[rr][je]);
            }
    }

    const float* g0 = lng + ((size_t)(blk * 2 + 0) * HH + h) * HD;
    const float* b0 = lnb + ((size_t)(blk * 2 + 0) * HH + h) * HD;
    const float* g1 = lng + ((size_t)(blk * 2 + 1) * HH + h) * HD;
    const float* b1 = lnb + ((size_t)(blk * 2 + 1) * HH + h) * HD;

    float hacc[4][4];
#pragma unroll
    for (int rr = 0; rr < 4; ++rr) {
        const int rg = r0 + tr * 4 + rr;
        const int l  = rg & (LL - 1);
        const float* vrow = vs + (size_t)l * HD;

        float vv[4], s1 = 0.f, s2 = 0.f;
#pragma unroll
        for (int je = 0; je < 4; ++je) {
            vv[je] = v0[rr][je] + vrow[tc + 16 * je];
            s1 += vv[je]; s2 += vv[je] * vv[je];
        }
#pragma unroll
        for (int m = 1; m <= 8; m <<= 1) { s1 += __shfl_xor(s1, m); s2 += __shfl_xor(s2, m); }
        float mean = s1 * (1.f / HD);
        float rstd = rsqrtf(s2 * (1.f / HD) - mean * mean + 1e-5f);
#pragma unroll
        for (int je = 0; je < 4; ++je) {
            const int e = tc + 16 * je;
            hacc[rr][je] = (vv[je] - mean) * rstd * g0[e] + b0[e] + v0[rr][je];
        }

        s1 = 0.f; s2 = 0.f;
#pragma unroll
        for (int je = 0; je < 4; ++je) {
            vv[je] = v1[rr][je] + vrow[tc + 16 * je];
            s1 += vv[je]; s2 += vv[je] * vv[je];
        }
#pragma unroll
        for (int m = 1; m <= 8; m <<= 1) { s1 += __shfl_xor(s1, m); s2 += __shfl_xor(s2, m); }
        mean = s1 * (1.f / HD);
        rstd = rsqrtf(s2 * (1.f / HD) - mean * mean + 1e-5f);
#pragma unroll
        for (int je = 0; je < 4; ++je) {
            const int e = tc + 16 * je;
            hacc[rr][je] += (vv[je] - mean) * rstd * g1[e] + b1[e] + v1[rr][je];
        }
    }

    __syncthreads();
#pragma unroll
    for (int rr = 0; rr < 4; ++rr)
#pragma unroll
        for (int je = 0; je < 4; ++je)
            xs[tr * 4 + rr][tc + 16 * je] = hacc[rr][je];
    __syncthreads();
#pragma unroll
    for (int i = 0; i < 4; ++i) {
        const int f = t + 256 * i;
        const int r = f >> 4;
        const int q = (f & 15) * 4;
        const float4 v = *(const float4*)&xs[r][q];
        us4 hi4, lo4;
        hi4.x = f2bf(v.x); lo4.x = f2bf(v.x - bf2f(hi4.x));
        hi4.y = f2bf(v.y); lo4.y = f2bf(v.y - bf2f(hi4.y));
        hi4.z = f2bf(v.z); lo4.z = f2bf(v.z - bf2f(hi4.z));
        hi4.w = f2bf(v.w); lo4.w = f2bf(v.w - bf2f(hi4.w));
        const size_t o = (size_t)(r0 + r) * EE + h * HD + q;
        *(us4*)(hhi + o) = hi4;
        *(us4*)(hlo + o) = lo4;
    }
}

// ---------------------------------------------------------------------------
// K3: MFMA GEMM  C[m,o] = act( sum_k A[m,k]*W[o,k] + bias[o] )
// 3-term bf16 split: Ahi*Whi + Alo*Whi + Ahi*Wlo  (error ~2^-16 rel).
// BM=64, BN=128, BK=32; 256 thr = 4 waves (2M x 2N); wave tile 32x64.
// LDS 24KB, k-outer layout [kg][row][8] (BW-floor-optimal ds_read_b128).
// A staged from [row][k] hi/lo planes; W from k_prep_w's linear blocked form.
// grid (128, 4) -> 512 blocks, 2/CU.
// ---------------------------------------------------------------------------
template <bool RELU, bool OUT_BF16>
__global__ __launch_bounds__(256) void k_gemm_mfma(
    const unsigned short* __restrict__ Ahi, const unsigned short* __restrict__ Alo,
    const unsigned short* __restrict__ Wb, const float* __restrict__ bias,
    unsigned short* __restrict__ Ohi, unsigned short* __restrict__ Olo,
    float* __restrict__ Of)
{
    __shared__ short lds[12288];   // bytes: Ahi[0,4K) Alo[4K,8K) Whi[8K,16K) Wlo[16K,24K)
    const int t    = threadIdx.x;
    const int lane = t & 63;
    const int wid  = t >> 6;
    const int kg   = lane >> 4;
    const int ln   = lane & 15;
    const int wm   = wid >> 1;
    const int wn   = wid & 1;
    const int r0   = blockIdx.x * 64;
    const int c0   = blockIdx.y * 128;

    f32x4 acc[2][4];
#pragma unroll
    for (int mf = 0; mf < 2; ++mf)
#pragma unroll
        for (int nf = 0; nf < 4; ++nf)
            acc[mf][nf] = (f32x4){0.f, 0.f, 0.f, 0.f};

    const unsigned short* gA0 = Ahi + (size_t)(r0 + lane) * EE + wid * 8;
    const unsigned short* gA1 = Alo + (size_t)(r0 + lane) * EE + wid * 8;
    const unsigned short* gW0 = Wb + (size_t)blockIdx.y * 16 * 4096
                              + wid * 1024 + lane * 8;
    const unsigned short* gW1 = gW0 + 262144;
    char* L = (char*)lds;

    for (int ks = 0; ks < 16; ++ks) {
        gload16(gA0 + ks * 32,          L + wid * 1024);
        gload16(gA1 + ks * 32,          L + 4096 + wid * 1024);
        gload16(gW0 + ks * 4096,        L + 8192 + wid * 2048);
        gload16(gW0 + ks * 4096 + 512,  L + 8192 + wid * 2048 + 1024);
        gload16(gW1 + ks * 4096,        L + 16384 + wid * 2048);
        gload16(gW1 + ks * 4096 + 512,  L + 16384 + wid * 2048 + 1024);
        __syncthreads();

        bf16x8 ah[2], al[2];
#pragma unroll
        for (int mf = 0; mf < 2; ++mf) {
            const int ao = kg * 1024 + (wm * 32 + mf * 16 + ln) * 16;
            ah[mf] = *(const bf16x8*)(L + ao);
            al[mf] = *(const bf16x8*)(L + 4096 + ao);
        }
#pragma unroll
        for (int nf = 0; nf < 4; ++nf) {
            const int wo = kg * 2048 + (wn * 64 + nf * 16 + ln) * 16;
            const bf16x8 wh = *(const bf16x8*)(L + 8192 + wo);
            const bf16x8 wl = *(const bf16x8*)(L + 16384 + wo);
#pragma unroll
            for (int mf = 0; mf < 2; ++mf) {
                acc[mf][nf] = __builtin_amdgcn_mfma_f32_16x16x32_bf16(ah[mf], wh, acc[mf][nf], 0, 0, 0);
                acc[mf][nf] = __builtin_amdgcn_mfma_f32_16x16x32_bf16(al[mf], wh, acc[mf][nf], 0, 0, 0);
                acc[mf][nf] = __builtin_amdgcn_mfma_f32_16x16x32_bf16(ah[mf], wl, acc[mf][nf], 0, 0, 0);
            }
        }
        __syncthreads();
    }

    // Epilogue. C/D frag map: col = ln, row = kg*4 + j  [m89-verified]
#pragma unroll
    for (int nf = 0; nf < 4; ++nf) {
        const int col = c0 + wn * 64 + nf * 16 + ln;
        const float bv = bias[col];
#pragma unroll
        for (int mf = 0; mf < 2; ++mf) {
            const int rbase = r0 + wm * 32 + mf * 16 + kg * 4;
#pragma unroll
            for (int j = 0; j < 4; ++j) {
                float v = acc[mf][nf][j] + bv;
                if (RELU) v = fmaxf(v, 0.f);
                const size_t o = (size_t)(rbase + j) * EE + col;
                if (OUT_BF16) {
                    const unsigned short h = f2bf(v);
                    Ohi[o] = h;
                    Olo[o] = f2bf(v - bf2f(h));
                } else {
                    Of[o] = v;
                }
            }
        }
    }
}

// ---------------------------------------------------------------------------
// K4: row LayerNorm over E=512
// ---------------------------------------------------------------------------
__global__ __launch_bounds__(256) void k_ln(const float* __restrict__ X,
                                            const float* __restrict__ g,
                                            const float* __restrict__ b,
                                            float* __restrict__ out)
{
    const int row  = blockIdx.x * 4 + (threadIdx.x >> 6);
    const int lane = threadIdx.x & 63;
    const float* xr = X + (size_t)row * EE;
    const int c0 = lane * 8;
    const float4 u = *(const float4*)(xr + c0);
    const float4 w = *(const float4*)(xr + c0 + 4);
    float s = u.x + u.y + u.z + u.w + w.x + w.y + w.z + w.w;
    float q = u.x*u.x + u.y*u.y + u.z*u.z + u.w*u.w
            + w.x*w.x + w.y*w.y + w.z*w.z + w.w*w.w;
#pragma unroll
    for (int m = 1; m < 64; m <<= 1) { s += __shfl_xor(s, m); q += __shfl_xor(q, m); }
    const float mean = s * (1.f / EE);
    const float rstd = rsqrtf(q * (1.f / EE) - mean * mean + 1e-5f);
    const float4 g0 = *(const float4*)(g + c0);
    const float4 g1 = *(const float4*)(g + c0 + 4);
    const float4 b0 = *(const float4*)(b + c0);
    const float4 b1 = *(const float4*)(b + c0 + 4);
    float4 o0, o1;
    o0.x = (u.x - mean) * rstd * g0.x + b0.x;
    o0.y = (u.y - mean) * rstd * g0.y + b0.y;
    o0.z = (u.z - mean) * rstd * g0.z + b0.z;
    o0.w = (u.w - mean) * rstd * g0.w + b0.w;
    o1.x = (w.x - mean) * rstd * g1.x + b1.x;
    o1.y = (w.y - mean) * rstd * g1.y + b1.y;
    o1.z = (w.z - mean) * rstd * g1.z + b1.z;
    o1.w = (w.w - mean) * rstd * g1.w + b1.w;
    float* orow = out + (size_t)row * EE;
    *(float4*)(orow + c0)     = o0;
    *(float4*)(orow + c0 + 4) = o1;
}

// ---------------------------------------------------------------------------
// Host launch. Inputs: 0 treat 1 outc 2 cov 3 active(unused) 4 kpe(DEAD)
// 5 vpe 6 Wv 7 Wk(DEAD) 8 Wq(DEAD) 9 ln_g 10 ln_b 11 ffW1 12 ffb1 13 ffW2
// 14 ffb2 15 fln_g 16 fln_b
// ---------------------------------------------------------------------------
extern "C" void kernel_launch(void* const* d_in, const int* in_sizes, int n_in,
                              void* d_out, int out_size, void* d_ws, size_t ws_size,
                              hipStream_t stream)
{
    const float* treat = (const float*)d_in[0];
    const float* outc  = (const float*)d_in[1];
    const float* cov   = (const float*)d_in[2];
    const float* vpe   = (const float*)d_in[5];
    const float* Wv    = (const float*)d_in[6];
    const float* lng   = (const float*)d_in[9];
    const float* lnb   = (const float*)d_in[10];
    const float* W1    = (const float*)d_in[11];
    const float* b1    = (const float*)d_in[12];
    const float* W2    = (const float*)d_in[13];
    const float* b2    = (const float*)d_in[14];
    const float* fg    = (const float*)d_in[15];
    const float* fb    = (const float*)d_in[16];
    float* out = (float*)d_out;

    char* w = (char*)d_ws;
    float*          vs   = (float*)w;          w += (size_t)LL * HD * 4;      // 256KB
    unsigned short* hbhi = (unsigned short*)w; w += (size_t)BL * EE * 2;      // 8MB
    unsigned short* hblo = (unsigned short*)w; w += (size_t)BL * EE * 2;
    unsigned short* ffhi = (unsigned short*)w; w += (size_t)BL * EE * 2;
    unsigned short* fflo = (unsigned short*)w; w += (size_t)BL * EE * 2;
    float*          hbf  = (float*)w;          w += (size_t)BL * EE * 4;      // 16MB
    unsigned short* Wb1  = (unsigned short*)w; w += (size_t)3 * 524288 * 2;   // 3MB
    unsigned short* Wb2  = (unsigned short*)w;

    k_prep_w<<<3072, 256, 0, stream>>>(W1, W2, Wb1, Wb2);
    k_vpe_sum<<<LL, 256, 0, stream>>>(vpe, vs);

    const float* xs_[3] = {treat, outc, cov};
    const float* zs_[3] = {cov, treat, outc};
    for (int i = 0; i < 3; ++i) {
        k_mha_pair<<<dim3(BL / 64, HH), 256, 0, stream>>>(
            xs_[i], zs_[i], Wv, lng, lnb, vs, hbhi, hblo, i);
        k_gemm_mfma<true, true><<<dim3(BL / 64, 4), 256, 0, stream>>>(
            hbhi, hblo, Wb1 + (size_t)i * 524288, b1 + i * EE, ffhi, fflo, nullptr);
        k_gemm_mfma<false, false><<<dim3(BL / 64, 4), 256, 0, stream>>>(
            ffhi, fflo, Wb2 + (size_t)i * 524288, b2 + i * EE, nullptr, nullptr, hbf);
        k_ln<<<BL / 4, 256, 0, stream>>>(hbf, fg + i * EE, fb + i * EE,
                                         out + (size_t)i * BL * EE);
    }
}